// Round 6
// baseline (1797121.094 us; speedup 1.0000x reference)
//
#include <hip/hip_runtime.h>

#define B_   64
#define T_   512
#define DIN  300
#define H_   512
#define TWOH 1024
#define R_   256
#define KX   320            // DIN padded to mult of 32
#define RETRY_CAP 2048      // hang-proof: bail to wrong-result, not to hang

typedef __attribute__((ext_vector_type(8))) short short8;
typedef __attribute__((ext_vector_type(4))) float f32x4;

__device__ __forceinline__ unsigned short f2bf(float f) {
  union { float f; unsigned int u; } v; v.f = f;
  unsigned int u = v.u;
  u += 0x7fffu + ((u >> 16) & 1u);   // RTN
  return (unsigned short)(u >> 16);
}
__device__ __forceinline__ float bf2f(unsigned short h) {
  union { unsigned int u; float f; } v; v.u = ((unsigned int)h) << 16;
  return v.f;
}

// h store: LLC write-through (sc0 sc1), value carries parity in bf16 LSB.
__device__ __forceinline__ void h_st16(unsigned short* p, unsigned int v) {
  asm volatile("global_store_short %0, %1, off sc0 sc1"
               :: "v"(p), "v"(v) : "memory");
}

// 16 x b128 h-loads (one wave's full K=512 A-slice), issued back-to-back,
// single vmcnt(0) inside the asm block. sc0 sc1 = LLC-coherent read.
#define LD16_BODY                                                 \
    "global_load_dwordx4 %0, %16, off sc0 sc1\n\t"                \
    "global_load_dwordx4 %1, %16, off offset:64 sc0 sc1\n\t"      \
    "global_load_dwordx4 %2, %16, off offset:128 sc0 sc1\n\t"     \
    "global_load_dwordx4 %3, %16, off offset:192 sc0 sc1\n\t"     \
    "global_load_dwordx4 %4, %16, off offset:256 sc0 sc1\n\t"     \
    "global_load_dwordx4 %5, %16, off offset:320 sc0 sc1\n\t"     \
    "global_load_dwordx4 %6, %16, off offset:384 sc0 sc1\n\t"     \
    "global_load_dwordx4 %7, %16, off offset:448 sc0 sc1\n\t"     \
    "global_load_dwordx4 %8, %16, off offset:512 sc0 sc1\n\t"     \
    "global_load_dwordx4 %9, %16, off offset:576 sc0 sc1\n\t"     \
    "global_load_dwordx4 %10, %16, off offset:640 sc0 sc1\n\t"    \
    "global_load_dwordx4 %11, %16, off offset:704 sc0 sc1\n\t"    \
    "global_load_dwordx4 %12, %16, off offset:768 sc0 sc1\n\t"    \
    "global_load_dwordx4 %13, %16, off offset:832 sc0 sc1\n\t"    \
    "global_load_dwordx4 %14, %16, off offset:896 sc0 sc1\n\t"    \
    "global_load_dwordx4 %15, %16, off offset:960 sc0 sc1\n\t"    \
    "s_waitcnt vmcnt(0)"
#define LD16_OUTS                                              \
      "=v"(hv[0]), "=v"(hv[1]), "=v"(hv[2]), "=v"(hv[3]),      \
      "=v"(hv[4]), "=v"(hv[5]), "=v"(hv[6]), "=v"(hv[7]),      \
      "=v"(hv[8]), "=v"(hv[9]), "=v"(hv[10]), "=v"(hv[11]),    \
      "=v"(hv[12]), "=v"(hv[13]), "=v"(hv[14]), "=v"(hv[15])

__device__ __forceinline__ void h_ld16(const unsigned int* p, uint4 hv[16]) {
  asm volatile(LD16_BODY : LD16_OUTS : "v"(p) : "memory");
}

// ---------------------------------------------------------------------------
// K0: X fp32 [B,T,300] -> Xbf bf16 [B,T,320] (zero-padded cols 300..319)
// ---------------------------------------------------------------------------
__global__ __launch_bounds__(256) void k_xbf(
    const float* __restrict__ X, unsigned short* __restrict__ Xbf)
{
  const int id = blockIdx.x * 256 + threadIdx.x;      // B*T*40 items
  if (id >= B_ * T_ * 40) return;
  const int row = id / 40, c = id % 40, k = c * 8;
  const float* src = X + (long long)row * DIN + k;
  short8 v;
#pragma unroll
  for (int i = 0; i < 8; ++i)
    v[i] = (short)((k + i < DIN) ? f2bf(src[i]) : (unsigned short)0);
  *(short8*)(Xbf + (long long)row * KX + k) = v;
}

// ---------------------------------------------------------------------------
// K1: persistent bidirectional GRU — wave-autonomous, barrier-free,
// parity-tagged h exchange (no flags, no drains, no fences).
//   256 waves = 8 groups (dir x batch-chunk-of-16) x 32 unit-slices of 16.
//   Per wave: Whh B-frags for ALL 3 gates of its 16 units (192 VGPR) +
//   Wih frags (120 VGPR). Per step: x-path MFMAs, retry-load h[t-1] burst
//   (every bf16's LSB == (t-1)&1 proves freshness), 48 h-MFMAs, elementwise
//   fully in-register (D-layout: lane = (unit=lr, batch=lq*4+j), r/z/n accs
//   element-aligned), store h with LSB=t&1 (sc0 sc1 write-through).
//   fp32 carried state lives in 4 VGPRs; masked rows store 0 (consumers'
//   gh rows for masked batches are discarded by their own valid mask).
// ---------------------------------------------------------------------------
__global__ __launch_bounds__(256) void k_gru(
    const unsigned short* __restrict__ Xbf,
    const float* __restrict__ Wih_f, const float* __restrict__ Whh_f,
    const float* __restrict__ bih_f, const float* __restrict__ bhh_f,
    const float* __restrict__ Wih_b, const float* __restrict__ Whh_b,
    const float* __restrict__ bih_b, const float* __restrict__ bhh_b,
    const int*  __restrict__ lens,
    unsigned short* __restrict__ hcat)        // [B][T][1024] bf16
{
  const int gid = blockIdx.x * 4 + (threadIdx.x >> 6);  // wave id 0..255
  const int g7 = gid & 7, sl = gid >> 3;
  const int dir = g7 & 1, bc = g7 >> 1;
  const int b0 = bc * 16, u0 = sl * 16;
  const int ln = threadIdx.x & 63, lr = ln & 15, lq = ln >> 4;

  const float* Wih = dir ? Wih_b : Wih_f;
  const float* Whh = dir ? Whh_b : Whh_f;
  const float* bih = dir ? bih_b : bih_f;
  const float* bhh = dir ? bhh_b : bhh_f;

  // per-lane biases (unit = u0+lr) and lengths (batches lq*4+j)
  float bi[3], bh[3];
#pragma unroll
  for (int g = 0; g < 3; ++g) {
    bi[g] = bih[g * H_ + u0 + lr];
    bh[g] = bhh[g * H_ + u0 + lr];
  }
  int len4[4];
#pragma unroll
  for (int j = 0; j < 4; ++j) len4[j] = lens[b0 + lq * 4 + j];

  // ---- persistent B-fragments: 3 gates x {Whh 16 frags, Wih 10 frags} ----
  short8 wh[3][16], wx[3][10];
#pragma unroll
  for (int g = 0; g < 3; ++g) {
    const int grow = g * H_ + u0 + lr;
    const float* wr = Whh + (long long)grow * H_;
#pragma unroll
    for (int kk = 0; kk < 16; ++kk) {
      const int k = kk * 32 + lq * 8;
      const float4 x0 = *(const float4*)(wr + k);
      const float4 x1 = *(const float4*)(wr + k + 4);
      short8 f;
      f[0] = (short)f2bf(x0.x); f[1] = (short)f2bf(x0.y);
      f[2] = (short)f2bf(x0.z); f[3] = (short)f2bf(x0.w);
      f[4] = (short)f2bf(x1.x); f[5] = (short)f2bf(x1.y);
      f[6] = (short)f2bf(x1.z); f[7] = (short)f2bf(x1.w);
      wh[g][kk] = f;
    }
    const float* wr2 = Wih + (long long)grow * DIN;
#pragma unroll
    for (int kk = 0; kk < 10; ++kk) {
      const int k = kk * 32 + lq * 8;
      short8 f;
#pragma unroll
      for (int i = 0; i < 8; ++i) {
        const float v = (k + i < DIN) ? wr2[k + i] : 0.f;
        f[i] = (short)f2bf(v);
      }
      wx[g][kk] = f;
    }
  }

  float hold[4] = {0.f, 0.f, 0.f, 0.f};   // exact fp32 carried state

  for (int t = 0; t < T_; ++t) {
    const int te = dir ? (T_ - 1 - t) : t;

    // ---- x-path: 30 MFMAs, independent of other waves ----
    f32x4 ax0 = (f32x4){0,0,0,0}, ax1 = (f32x4){0,0,0,0}, ax2 = (f32x4){0,0,0,0};
    {
      const unsigned short* xb = Xbf + ((long long)(b0 + lr) * T_ + te) * KX;
#pragma unroll
      for (int kk = 0; kk < 10; ++kk) {
        const short8 a = *(const short8*)(xb + kk * 32 + lq * 8);
        ax0 = __builtin_amdgcn_mfma_f32_16x16x32_bf16(a, wx[0][kk], ax0, 0, 0, 0);
        ax1 = __builtin_amdgcn_mfma_f32_16x16x32_bf16(a, wx[1][kk], ax1, 0, 0, 0);
        ax2 = __builtin_amdgcn_mfma_f32_16x16x32_bf16(a, wx[2][kk], ax2, 0, 0, 0);
      }
    }

    // ---- h-path: parity-verified retry load of h[t-1], then 48 MFMAs ----
    f32x4 ah0 = (f32x4){0,0,0,0}, ah1 = (f32x4){0,0,0,0}, ah2 = (f32x4){0,0,0,0};
    if (t > 0) {
      const int tp = dir ? (te + 1) : (te - 1);
      const unsigned int pm = ((unsigned int)((t - 1) & 1)) * 0x00010001u;
      const unsigned int* hb32 = (const unsigned int*)
          (hcat + ((long long)(b0 + lr) * T_ + tp) * TWOH + dir * H_) + lq * 4;
      uint4 hv[16];
      bool ok = false;
      for (int spin = 0; spin < RETRY_CAP && !ok; ++spin) {
        h_ld16(hb32, hv);
        unsigned int e = 0;
#pragma unroll
        for (int kk = 0; kk < 16; ++kk)
          e |= (hv[kk].x ^ pm) | (hv[kk].y ^ pm) |
               (hv[kk].z ^ pm) | (hv[kk].w ^ pm);
        ok = __all((e & 0x00010001u) == 0u);
      }
#pragma unroll
      for (int kk = 0; kk < 16; ++kk) {
        union { uint4 u; short8 s; } c; c.u = hv[kk];
        ah0 = __builtin_amdgcn_mfma_f32_16x16x32_bf16(c.s, wh[0][kk], ah0, 0, 0, 0);
        ah1 = __builtin_amdgcn_mfma_f32_16x16x32_bf16(c.s, wh[1][kk], ah1, 0, 0, 0);
        ah2 = __builtin_amdgcn_mfma_f32_16x16x32_bf16(c.s, wh[2][kk], ah2, 0, 0, 0);
      }
    }

    // ---- elementwise fully in-register: lane = (unit u0+lr, batch lq*4+j) --
    const unsigned int pw = (unsigned int)(t & 1);
#pragma unroll
    for (int j = 0; j < 4; ++j) {
      const float rg = 1.f / (1.f + __expf(-(ax0[j] + ah0[j] + bi[0] + bh[0])));
      const float zg = 1.f / (1.f + __expf(-(ax1[j] + ah1[j] + bi[1] + bh[1])));
      const float ng = tanhf(ax2[j] + bi[2] + rg * (ah2[j] + bh[2]));
      const float hn = (1.f - zg) * ng + zg * hold[j];
      const bool valid = te < len4[j];
      const float hc = valid ? hn : hold[j];
      hold[j] = hc;
      unsigned int us = (unsigned int)f2bf(valid ? hc : 0.f);
      us = (us & 0xFFFEu) | pw;            // freshness tag in bf16 LSB
      h_st16(hcat + ((long long)(b0 + lq * 4 + j) * T_ + te) * TWOH
                  + dir * H_ + u0 + lr, us);
    }
  }
}

// ---------------------------------------------------------------------------
// K2: scores[b,t] = sum_r u_s[r] * tanh(Hcat[b,t,:] . g2r_W[r,:] + g2r_b[r])
// Block = 64 M-rows x full N=256, K=1024; reduce over r in-register.
// ---------------------------------------------------------------------------
__global__ __launch_bounds__(256) void k_scores(
    const unsigned short* __restrict__ hcat,   // [B*T][1024] bf16
    const float* __restrict__ g2rW,            // [256][1024]
    const float* __restrict__ g2rb,
    const float* __restrict__ us,
    float* __restrict__ scores)
{
  const int m0 = blockIdx.x * 64;
  const int tid = threadIdx.x;
  const int wv = tid >> 6, ln = tid & 63, lr = ln & 15, lq = ln >> 4;

  __shared__ unsigned short As[64 * 40];
  __shared__ unsigned short Bs[256 * 40];

  f32x4 acc[16];
#pragma unroll
  for (int j = 0; j < 16; ++j) acc[j] = (f32x4){0.f, 0.f, 0.f, 0.f};

  for (int kt = 0; kt < 32; ++kt) {
    const int k0 = kt * 32;
    __syncthreads();
#pragma unroll
    for (int h = 0; h < 2; ++h) {            // A: 64 rows x 32 bf16
      const int id = tid * 2 + h;
      const int row = id >> 3, kq = id & 7;
      *(uint2*)&As[row * 40 + kq * 4] =
          *(const uint2*)(hcat + (long long)(m0 + row) * TWOH + k0 + kq * 4);
    }
    {
      const float* src = g2rW + (long long)tid * TWOH + k0;
#pragma unroll
      for (int h = 0; h < 4; ++h) {          // B row = tid: 32 floats -> bf16
        const float4 v0 = *(const float4*)(src + h * 8);
        const float4 v1 = *(const float4*)(src + h * 8 + 4);
        short8 f;
        f[0] = (short)f2bf(v0.x); f[1] = (short)f2bf(v0.y);
        f[2] = (short)f2bf(v0.z); f[3] = (short)f2bf(v0.w);
        f[4] = (short)f2bf(v1.x); f[5] = (short)f2bf(v1.y);
        f[6] = (short)f2bf(v1.z); f[7] = (short)f2bf(v1.w);
        *(short8*)&Bs[tid * 40 + h * 8] = f;
      }
    }
    __syncthreads();
    const short8 a = *(const short8*)&As[(wv * 16 + lr) * 40 + lq * 8];
#pragma unroll
    for (int j = 0; j < 16; ++j) {
      const short8 b = *(const short8*)&Bs[(j * 16 + lr) * 40 + lq * 8];
      acc[j] = __builtin_amdgcn_mfma_f32_16x16x32_bf16(a, b, acc[j], 0, 0, 0);
    }
  }

  float part[4] = {0.f, 0.f, 0.f, 0.f};
#pragma unroll
  for (int j = 0; j < 16; ++j) {
    const int col = j * 16 + lr;
    const float bias = g2rb[col];
    const float uw = us[col];
#pragma unroll
    for (int r = 0; r < 4; ++r) part[r] += tanhf(acc[j][r] + bias) * uw;
  }
#pragma unroll
  for (int d = 1; d < 16; d <<= 1) {
#pragma unroll
    for (int r = 0; r < 4; ++r) part[r] += __shfl_xor(part[r], d, 64);
  }
  if (lr == 0) {
#pragma unroll
    for (int r = 0; r < 4; ++r) scores[m0 + wv * 16 + lq * 4 + r] = part[r];
  }
}

// ---------------------------------------------------------------------------
// K3: masked softmax over t per batch (block = batch, 512 threads)
// ---------------------------------------------------------------------------
__global__ __launch_bounds__(512) void k_softmax(
    const float* __restrict__ scores, const int* __restrict__ lens,
    float* __restrict__ wout)
{
  const int b = blockIdx.x;
  const int tid = threadIdx.x, ln = tid & 63, wid = tid >> 6;
  __shared__ float red[8];
  __shared__ float bcast;

  float s = scores[b * T_ + tid];
  if (tid >= lens[b]) s = -1e30f;

  float m = s;
#pragma unroll
  for (int d = 32; d; d >>= 1) m = fmaxf(m, __shfl_xor(m, d, 64));
  if (!ln) red[wid] = m;
  __syncthreads();
  if (tid == 0) {
    float mm = red[0];
#pragma unroll
    for (int i = 1; i < 8; ++i) mm = fmaxf(mm, red[i]);
    bcast = mm;
  }
  __syncthreads();
  const float mx = bcast;

  float e = __expf(s - mx);
  float sum = e;
#pragma unroll
  for (int d = 32; d; d >>= 1) sum += __shfl_xor(sum, d, 64);
  __syncthreads();
  if (!ln) red[wid] = sum;
  __syncthreads();
  if (tid == 0) {
    float ss = 0.f;
#pragma unroll
    for (int i = 0; i < 8; ++i) ss += red[i];
    bcast = ss;
  }
  __syncthreads();
  wout[b * T_ + tid] = e / bcast;
}

// ---------------------------------------------------------------------------
// K4: pooled[b][h] += sum_t w[b,t] * Hcat[b,t,h]   (block = (b, t-chunk 128))
// ---------------------------------------------------------------------------
__global__ __launch_bounds__(256) void k_pool(
    const unsigned short* __restrict__ hcat, const float* __restrict__ wsm,
    float* __restrict__ pooled)
{
  const int b = blockIdx.x >> 2, tc = blockIdx.x & 3;
  const int t0 = tc * 128;
  const int tid = threadIdx.x;
  __shared__ float w_s[128];
  if (tid < 128) w_s[tid] = wsm[b * T_ + t0 + tid];
  __syncthreads();
#pragma unroll
  for (int hc = 0; hc < 4; ++hc) {
    const int h = hc * 256 + tid;
    float acc = 0.f;
    for (int tt = 0; tt < 128; ++tt)
      acc += w_s[tt] * bf2f(hcat[((long long)b * T_ + t0 + tt) * TWOH + h]);
    atomicAdd(&pooled[b * TWOH + h], acc);
  }
}

// ---------------------------------------------------------------------------
// K5: out[b] = sigmoid(pooled[b] . r2o_W + r2o_b)
// ---------------------------------------------------------------------------
__global__ __launch_bounds__(256) void k_out(
    const float* __restrict__ pooled, const float* __restrict__ r2oW,
    const float* __restrict__ r2ob, float* __restrict__ out)
{
  const int b = blockIdx.x;
  const int tid = threadIdx.x, ln = tid & 63, wid = tid >> 6;
  __shared__ float red[4];
  float a = 0.f;
  for (int h = tid; h < TWOH; h += 256) a += pooled[b * TWOH + h] * r2oW[h];
#pragma unroll
  for (int d = 32; d; d >>= 1) a += __shfl_xor(a, d, 64);
  if (!ln) red[wid] = a;
  __syncthreads();
  if (tid == 0) {
    const float s = red[0] + red[1] + red[2] + red[3] + r2ob[0];
    out[b] = 1.f / (1.f + expf(-s));
  }
}

// ---------------------------------------------------------------------------
extern "C" void kernel_launch(void* const* d_in, const int* in_sizes, int n_in,
                              void* d_out, int out_size, void* d_ws, size_t ws_size,
                              hipStream_t stream) {
  const float* X     = (const float*)d_in[0];
  const int*   lens  = (const int*)d_in[1];
  const float* Wih_f = (const float*)d_in[3];
  const float* Whh_f = (const float*)d_in[4];
  const float* bih_f = (const float*)d_in[5];
  const float* bhh_f = (const float*)d_in[6];
  const float* Wih_b = (const float*)d_in[7];
  const float* Whh_b = (const float*)d_in[8];
  const float* bih_b = (const float*)d_in[9];
  const float* bhh_b = (const float*)d_in[10];
  const float* g2rW  = (const float*)d_in[11];
  const float* g2rb  = (const float*)d_in[12];
  const float* us    = (const float*)d_in[13];
  const float* r2oW  = (const float*)d_in[14];
  const float* r2ob  = (const float*)d_in[15];

  // workspace layout (non-overlapping, ~84.5 MiB total)
  char* ws = (char*)d_ws;
  unsigned short* Xbf    = (unsigned short*)(ws + 0LL);         // 20 MiB
  unsigned short* hcat   = (unsigned short*)(ws + 20971520LL);  // 64 MiB
  float*          scores = (float*)         (ws + 88096768LL);  // 128 KiB
  float*          wsm    = (float*)         (ws + 88227840LL);  // 128 KiB
  float*          pooled = (float*)         (ws + 88358912LL);  // 256 KiB
  if (ws_size < 88621056ULL) return;  // fail cleanly (absmax), don't scribble

  hipMemsetAsync(pooled, 0, 262144, stream);

  k_xbf<<<5120, 256, 0, stream>>>(X, Xbf);
  k_gru<<<64, 256, 0, stream>>>(Xbf, Wih_f, Whh_f, bih_f, bhh_f,
                                Wih_b, Whh_b, bih_b, bhh_b, lens, hcat);
  k_scores<<<512, 256, 0, stream>>>(hcat, g2rW, g2rb, us, scores);
  k_softmax<<<64, 512, 0, stream>>>(scores, lens, wsm);
  k_pool<<<256, 256, 0, stream>>>(hcat, wsm, pooled);
  k_out<<<64, 256, 0, stream>>>(pooled, r2oW, r2ob, (float*)d_out);
}